// Round 3
// 827.553 us; speedup vs baseline: 1.2065x; 1.2065x over previous
//
#include <hip/hip_runtime.h>
#include <hip/hip_bf16.h>
#include <math.h>

#define T_TOK 2048
#define H_DIM 1024
#define NHH 16
#define NKVH 4
#define HD 64
#define QKV_N 1536   // (16 + 2*4) * 64
#define NE 64
#define NGRP 8
#define TKG 4
#define TOPKK 8
#define EI 256
#define ISH 512
#define NPOS (T_TOK * TOPKK)   // 16384 expert-token slots

typedef __bf16 bf16_t;
typedef bf16_t bf16x8 __attribute__((ext_vector_type(8)));
typedef bf16_t bf16x4v __attribute__((ext_vector_type(4)));
typedef float f32x4 __attribute__((ext_vector_type(4)));

#define MFMA_BF16 __builtin_amdgcn_mfma_f32_16x16x32_bf16

// ---------------- RMSNorm -> optional f32 out + bf16 out ----------------
__global__ void rmsnorm_k(const float* __restrict__ x, const float* __restrict__ w,
                          float* __restrict__ outf, bf16_t* __restrict__ outb) {
  const int t = blockIdx.x;
  const int tid = threadIdx.x;
  const float* xp = x + (size_t)t * H_DIM;
  const float4 x4 = *(const float4*)(xp + tid * 4);
  float s = x4.x * x4.x + x4.y * x4.y + x4.z * x4.z + x4.w * x4.w;
#pragma unroll
  for (int off = 32; off >= 1; off >>= 1) s += __shfl_xor(s, off);
  __shared__ float red[4];
  if ((tid & 63) == 0) red[tid >> 6] = s;
  __syncthreads();
  const float tot = red[0] + red[1] + red[2] + red[3];
  const float r = rsqrtf(tot / (float)H_DIM + 1e-6f);
  const float4 w4 = *(const float4*)(w + tid * 4);
  float4 o;
  o.x = x4.x * r * w4.x; o.y = x4.y * r * w4.y;
  o.z = x4.z * r * w4.z; o.w = x4.w * r * w4.w;
  if (outf) *(float4*)(outf + (size_t)t * H_DIM + tid * 4) = o;
  bf16x4v ob;
  ob[0] = (bf16_t)o.x; ob[1] = (bf16_t)o.y; ob[2] = (bf16_t)o.z; ob[3] = (bf16_t)o.w;
  *(bf16x4v*)(outb + (size_t)t * H_DIM + tid * 4) = ob;
}

// ---------------- transpose-cast f32 [R][C] -> bf16 [C][R] (per-expert strides) ----
__global__ void castT_k(const float* __restrict__ src, bf16_t* __restrict__ dst,
                        int R, int C, size_t srcStride, size_t dstStride,
                        int dstLD, int rowOff) {
  const int e = blockIdx.z;
  const float* sp = src + (size_t)e * srcStride;
  bf16_t* dp = dst + (size_t)e * dstStride;
  const int r0 = blockIdx.y * 32, c0 = blockIdx.x * 32;
  const int tid = threadIdx.x;
  __shared__ float tl[32][33];
  {
    const int rr = tid >> 3, cc4 = (tid & 7) * 4;
    const float4 v = *(const float4*)(sp + (size_t)(r0 + rr) * C + c0 + cc4);
    tl[rr][cc4 + 0] = v.x; tl[rr][cc4 + 1] = v.y;
    tl[rr][cc4 + 2] = v.z; tl[rr][cc4 + 3] = v.w;
  }
  __syncthreads();
  {
    const int cc = tid >> 3, rr4 = (tid & 7) * 4;
    bf16x4v o;
#pragma unroll
    for (int i = 0; i < 4; i++) o[i] = (bf16_t)tl[rr4 + i][cc];
    *(bf16x4v*)(dp + (size_t)(rowOff + c0 + cc) * dstLD + r0 + rr4) = o;
  }
}

// ---------------- MFMA GEMM: C[M,N] f32 = A[M,K]bf16 @ Bt[N,K]bf16 (+add0)(+add1) ----
// 256 thr = 4 waves (2x2), tile 128x128, BK=64, fragment-major LDS.
__global__ __launch_bounds__(256) void mfma_gemm_k(
    const bf16_t* __restrict__ A, const bf16_t* __restrict__ Bt,
    const float* __restrict__ add0, const float* __restrict__ add1,
    float* __restrict__ C, int M, int N, int K) {
  __shared__ bf16_t Al[128 * 64];
  __shared__ bf16_t Bl[128 * 64];
  const int tid = threadIdx.x;
  const int lane = tid & 63, wave = tid >> 6;
  const int wm = wave >> 1, wn = wave & 1;
  const int lrow = lane & 15, lq = lane >> 4;
  const int m0 = blockIdx.y * 128, n0 = blockIdx.x * 128;
  const int arow = tid >> 1, qb = (tid & 1) * 4;
  const bf16_t* Arow = A + (size_t)(m0 + arow) * K + qb * 8;
  const bf16_t* Brow = Bt + (size_t)(n0 + arow) * K + qb * 8;
  f32x4 acc[4][4];
#pragma unroll
  for (int i = 0; i < 4; i++)
#pragma unroll
    for (int j = 0; j < 4; j++) acc[i][j] = (f32x4){0.f, 0.f, 0.f, 0.f};
  for (int k0 = 0; k0 < K; k0 += 64) {
    __syncthreads();
#pragma unroll
    for (int i = 0; i < 4; i++) {
      const int q = qb + i;
      *(bf16x8*)&Al[(q * 128 + arow) * 8] = *(const bf16x8*)(Arow + k0 + i * 8);
      *(bf16x8*)&Bl[(q * 128 + arow) * 8] = *(const bf16x8*)(Brow + k0 + i * 8);
    }
    __syncthreads();
#pragma unroll
    for (int kb = 0; kb < 2; kb++) {
      bf16x8 af[4], bfr[4];
#pragma unroll
      for (int i = 0; i < 4; i++) {
        af[i]  = *(const bf16x8*)&Al[((kb * 4 + lq) * 128 + wm * 64 + i * 16 + lrow) * 8];
        bfr[i] = *(const bf16x8*)&Bl[((kb * 4 + lq) * 128 + wn * 64 + i * 16 + lrow) * 8];
      }
#pragma unroll
      for (int i = 0; i < 4; i++)
#pragma unroll
        for (int j = 0; j < 4; j++)
          acc[i][j] = MFMA_BF16(af[i], bfr[j], acc[i][j], 0, 0, 0);
    }
  }
#pragma unroll
  for (int i = 0; i < 4; i++)
#pragma unroll
    for (int r = 0; r < 4; r++) {
      const int m = m0 + wm * 64 + i * 16 + lq * 4 + r;
#pragma unroll
      for (int j = 0; j < 4; j++) {
        const int n = n0 + wn * 64 + j * 16 + lrow;
        float v = acc[i][j][r];
        if (add0) v += add0[(size_t)m * N + n];
        if (add1) v += add1[(size_t)m * N + n];
        C[(size_t)m * N + n] = v;
      }
    }
}

// ---------------- MoE gate+up grouped MFMA GEMM: rows gathered via ptok ----------
// N=512 (gate cols 0..255, up cols 256..511 in weT), K=1024; out bf16 gu_e.
__global__ __launch_bounds__(256) void mfma_gateup_k(
    const bf16_t* __restrict__ h2b, const bf16_t* __restrict__ weT,
    const int* __restrict__ ptok, const int* __restrict__ offs,
    bf16_t* __restrict__ gu_e) {
  const int e = blockIdx.z;
  const int base = offs[e];
  const int cnt = offs[e + 1] - base;
  const int m0 = blockIdx.y * 128;
  if (m0 >= cnt) return;
  const int n0 = blockIdx.x * 128;
  __shared__ bf16_t Al[128 * 64];
  __shared__ bf16_t Bl[128 * 64];
  __shared__ int toks[128];
  const int tid = threadIdx.x;
  if (tid < 128) toks[tid] = ptok[base + min(m0 + tid, cnt - 1)];
  const int lane = tid & 63, wave = tid >> 6;
  const int wm = wave >> 1, wn = wave & 1;
  const int lrow = lane & 15, lq = lane >> 4;
  const int arow = tid >> 1, qb = (tid & 1) * 4;
  const bf16_t* Bt = weT + (size_t)e * 512 * 1024;
  const bf16_t* Brow = Bt + (size_t)(n0 + arow) * 1024 + qb * 8;
  f32x4 acc[4][4];
#pragma unroll
  for (int i = 0; i < 4; i++)
#pragma unroll
    for (int j = 0; j < 4; j++) acc[i][j] = (f32x4){0.f, 0.f, 0.f, 0.f};
  for (int k0 = 0; k0 < 1024; k0 += 64) {
    __syncthreads();
    const bf16_t* Arow = h2b + (size_t)toks[arow] * 1024 + qb * 8;
#pragma unroll
    for (int i = 0; i < 4; i++) {
      const int q = qb + i;
      *(bf16x8*)&Al[(q * 128 + arow) * 8] = *(const bf16x8*)(Arow + k0 + i * 8);
      *(bf16x8*)&Bl[(q * 128 + arow) * 8] = *(const bf16x8*)(Brow + k0 + i * 8);
    }
    __syncthreads();
#pragma unroll
    for (int kb = 0; kb < 2; kb++) {
      bf16x8 af[4], bfr[4];
#pragma unroll
      for (int i = 0; i < 4; i++) {
        af[i]  = *(const bf16x8*)&Al[((kb * 4 + lq) * 128 + wm * 64 + i * 16 + lrow) * 8];
        bfr[i] = *(const bf16x8*)&Bl[((kb * 4 + lq) * 128 + wn * 64 + i * 16 + lrow) * 8];
      }
#pragma unroll
      for (int i = 0; i < 4; i++)
#pragma unroll
        for (int j = 0; j < 4; j++)
          acc[i][j] = MFMA_BF16(af[i], bfr[j], acc[i][j], 0, 0, 0);
    }
  }
#pragma unroll
  for (int i = 0; i < 4; i++)
#pragma unroll
    for (int r = 0; r < 4; r++) {
      const int mloc = m0 + wm * 64 + i * 16 + lq * 4 + r;
      if (mloc < cnt) {
#pragma unroll
        for (int j = 0; j < 4; j++) {
          const int n = n0 + wn * 64 + j * 16 + lrow;
          gu_e[(size_t)(base + mloc) * 512 + n] = (bf16_t)acc[i][j][r];
        }
      }
    }
}

// ---------------- MoE down grouped MFMA GEMM: weighted atomicAdd into y ----------
// A = actb rows (already permuted), N=1024, K=256.
__global__ __launch_bounds__(256) void mfma_down_k(
    const bf16_t* __restrict__ actb, const bf16_t* __restrict__ wdT,
    const int* __restrict__ ptok, const float* __restrict__ pw,
    const int* __restrict__ offs, float* __restrict__ y) {
  const int e = blockIdx.z;
  const int base = offs[e];
  const int cnt = offs[e + 1] - base;
  const int m0 = blockIdx.y * 128;
  if (m0 >= cnt) return;
  const int n0 = blockIdx.x * 128;
  __shared__ bf16_t Al[128 * 64];
  __shared__ bf16_t Bl[128 * 64];
  const int tid = threadIdx.x;
  const int lane = tid & 63, wave = tid >> 6;
  const int wm = wave >> 1, wn = wave & 1;
  const int lrow = lane & 15, lq = lane >> 4;
  const int arow = tid >> 1, qb = (tid & 1) * 4;
  const int agrow = base + min(m0 + arow, cnt - 1);
  const bf16_t* Arow = actb + (size_t)agrow * 256 + qb * 8;
  const bf16_t* Brow = wdT + (size_t)e * 1024 * 256 + (size_t)(n0 + arow) * 256 + qb * 8;
  f32x4 acc[4][4];
#pragma unroll
  for (int i = 0; i < 4; i++)
#pragma unroll
    for (int j = 0; j < 4; j++) acc[i][j] = (f32x4){0.f, 0.f, 0.f, 0.f};
  for (int k0 = 0; k0 < 256; k0 += 64) {
    __syncthreads();
#pragma unroll
    for (int i = 0; i < 4; i++) {
      const int q = qb + i;
      *(bf16x8*)&Al[(q * 128 + arow) * 8] = *(const bf16x8*)(Arow + k0 + i * 8);
      *(bf16x8*)&Bl[(q * 128 + arow) * 8] = *(const bf16x8*)(Brow + k0 + i * 8);
    }
    __syncthreads();
#pragma unroll
    for (int kb = 0; kb < 2; kb++) {
      bf16x8 af[4], bfr[4];
#pragma unroll
      for (int i = 0; i < 4; i++) {
        af[i]  = *(const bf16x8*)&Al[((kb * 4 + lq) * 128 + wm * 64 + i * 16 + lrow) * 8];
        bfr[i] = *(const bf16x8*)&Bl[((kb * 4 + lq) * 128 + wn * 64 + i * 16 + lrow) * 8];
      }
#pragma unroll
      for (int i = 0; i < 4; i++)
#pragma unroll
        for (int j = 0; j < 4; j++)
          acc[i][j] = MFMA_BF16(af[i], bfr[j], acc[i][j], 0, 0, 0);
    }
  }
#pragma unroll
  for (int i = 0; i < 4; i++)
#pragma unroll
    for (int r = 0; r < 4; r++) {
      const int mloc = m0 + wm * 64 + i * 16 + lq * 4 + r;
      if (mloc < cnt) {
        const float wv = pw[base + mloc];
        const int tok = ptok[base + mloc];
#pragma unroll
        for (int j = 0; j < 4; j++) {
          const int n = n0 + wn * 64 + j * 16 + lrow;
          atomicAdd(&y[(size_t)tok * H_DIM + n], wv * acc[i][j][r]);
        }
      }
    }
}

// ---------------- RoPE (neox, in-place on q and k regions of qkv), f32 ----------------
__global__ void rope_k(float* __restrict__ qkv, const int* __restrict__ positions) {
  const int t = blockIdx.x, h = blockIdx.y;
  const int i = threadIdx.x;                  // 0..31
  const float inv = exp2f((float)i * (-13.287712379549449f / 32.0f));
  const float f = (float)positions[t] * inv;
  float sn, c;
  sincosf(f, &sn, &c);
  float* p = qkv + (size_t)t * QKV_N + h * HD;
  const float x1 = p[i], x2 = p[i + 32];
  p[i] = x1 * c - x2 * sn;
  p[i + 32] = x2 * c + x1 * sn;
}

// ---------------- MFMA flash attention, full hi/lo split (f32-equivalent) ------
// Grid: (NHH heads, T/64 q-tiles), heavy diagonal tiles first.
// Block: 256 thr = 4 waves; each wave owns 16 q-rows; KV tile = 64 cols.
// Fragment conventions match mfma_gemm_k: A/B stored [row][k],
// C layout row=(lane>>4)*4+r, col=lane&15.
// Precision: scores = qh*kh + qh*kl + ql*kh;  PV = ph*vh + ph*vl + pl*vh.
// All dropped terms are ~2^-18 relative.  Softmax in f32 registers.
// __syncthreads() between P-write and P-read: the relayout is cross-lane
// through LDS, which the compiler may otherwise legally reorder.
__global__ __launch_bounds__(256) void attn_k(const float* __restrict__ qkv,
                                              bf16_t* __restrict__ attnb) {
  const int h = blockIdx.x;
  const int qt = (T_TOK / 64 - 1) - blockIdx.y;   // heavy tiles first
  const int g = h >> 2;
  const int tid = threadIdx.x;
  const int lane = tid & 63, wave = tid >> 6;
  const int lcol = lane & 15, lk = lane >> 4;

  __shared__ bf16_t Kh[64][72];   // [kcol][d] hi part, stride 72 (16B-aligned rows)
  __shared__ bf16_t Ko[64][72];   // [kcol][d] lo part
  __shared__ bf16_t Vh[64][72];   // [d][(kcol + (d&56)) & 63]  rotated transpose, hi
  __shared__ bf16_t Vl[64][72];   // rotated transpose, lo
  __shared__ bf16_t Ph[64][72];   // [qrow_local][kcol] hi
  __shared__ bf16_t Po[64][72];   // [qrow_local][kcol] lo

  // --- Q fragments (hi/lo) in registers, pre-scaled by D^-1/2 ---
  bf16x8 aqh[2], aql[2];
  {
    const int qrow = qt * 64 + wave * 16 + lcol;
    const float* qp = qkv + (size_t)qrow * QKV_N + h * HD + lk * 8;
#pragma unroll
    for (int ks = 0; ks < 2; ks++) {
      const float4 a = *(const float4*)(qp + ks * 32);
      const float4 b = *(const float4*)(qp + ks * 32 + 4);
      const float qv[8] = {a.x, a.y, a.z, a.w, b.x, b.y, b.z, b.w};
#pragma unroll
      for (int j = 0; j < 8; j++) {
        const float v = qv[j] * 0.125f;
        const bf16_t hi = (bf16_t)v;
        aqh[ks][j] = hi;
        aql[ks][j] = (bf16_t)(v - (float)hi);
      }
    }
  }

  float m[4], l[4];
  f32x4 acc[4];
#pragma unroll
  for (int r = 0; r < 4; r++) { m[r] = -1e30f; l[r] = 0.f; }
#pragma unroll
  for (int n = 0; n < 4; n++) acc[n] = (f32x4){0.f, 0.f, 0.f, 0.f};

  const float* kbase = qkv + NHH * HD + g * HD;
  const float* vbase = qkv + (NHH + NKVH) * HD + g * HD;
  const int srow = tid >> 2;      // staging: token row 0..63
  const int scb = tid & 3;        // staging: 16-float col block

  for (int s0 = 0; s0 <= qt * 64; s0 += 64) {
    __syncthreads();
    // ---- stage K (hi/lo row-major) and V (hi/lo rotated transpose) ----
    {
      const float* kp = kbase + (size_t)(s0 + srow) * QKV_N + scb * 16;
      const float* vp = vbase + (size_t)(s0 + srow) * QKV_N + scb * 16;
      const float4 k0 = *(const float4*)(kp + 0);
      const float4 k1 = *(const float4*)(kp + 4);
      const float4 k2 = *(const float4*)(kp + 8);
      const float4 k3 = *(const float4*)(kp + 12);
      const float kv[16] = {k0.x, k0.y, k0.z, k0.w, k1.x, k1.y, k1.z, k1.w,
                            k2.x, k2.y, k2.z, k2.w, k3.x, k3.y, k3.z, k3.w};
      bf16x8 h0, h1, o0, o1;
#pragma unroll
      for (int j = 0; j < 8; j++) {
        const bf16_t hi = (bf16_t)kv[j];
        h0[j] = hi; o0[j] = (bf16_t)(kv[j] - (float)hi);
        const bf16_t hi2 = (bf16_t)kv[j + 8];
        h1[j] = hi2; o1[j] = (bf16_t)(kv[j + 8] - (float)hi2);
      }
      *(bf16x8*)&Kh[srow][scb * 16] = h0;
      *(bf16x8*)&Kh[srow][scb * 16 + 8] = h1;
      *(bf16x8*)&Ko[srow][scb * 16] = o0;
      *(bf16x8*)&Ko[srow][scb * 16 + 8] = o1;
      const float4 v0 = *(const float4*)(vp + 0);
      const float4 v1 = *(const float4*)(vp + 4);
      const float4 v2 = *(const float4*)(vp + 8);
      const float4 v3 = *(const float4*)(vp + 12);
      const float vv[16] = {v0.x, v0.y, v0.z, v0.w, v1.x, v1.y, v1.z, v1.w,
                            v2.x, v2.y, v2.z, v2.w, v3.x, v3.y, v3.z, v3.w};
#pragma unroll
      for (int r2 = 0; r2 < 16; r2++) {
        const int d = scb * 16 + r2;
        const int col = (srow + (d & 56)) & 63;
        const bf16_t hi = (bf16_t)vv[r2];
        Vh[d][col] = hi;
        Vl[d][col] = (bf16_t)(vv[r2] - (float)hi);
      }
    }
    __syncthreads();
    // ---- S = Q K^T  (per wave: 16 rows x 64 cols), 3-term hi/lo ----
    f32x4 s4[4];
#pragma unroll
    for (int n = 0; n < 4; n++) s4[n] = (f32x4){0.f, 0.f, 0.f, 0.f};
#pragma unroll
    for (int ks = 0; ks < 2; ks++) {
#pragma unroll
      for (int n = 0; n < 4; n++) {
        const bf16x8 bh = *(const bf16x8*)&Kh[n * 16 + lcol][ks * 32 + lk * 8];
        const bf16x8 bo = *(const bf16x8*)&Ko[n * 16 + lcol][ks * 32 + lk * 8];
        s4[n] = MFMA_BF16(aqh[ks], bh, s4[n], 0, 0, 0);
        s4[n] = MFMA_BF16(aqh[ks], bo, s4[n], 0, 0, 0);
        s4[n] = MFMA_BF16(aql[ks], bh, s4[n], 0, 0, 0);
      }
    }
    // ---- causal mask on diagonal tile ----
    if (s0 == qt * 64) {
#pragma unroll
      for (int n = 0; n < 4; n++) {
        const int col = n * 16 + lcol;
#pragma unroll
        for (int r = 0; r < 4; r++)
          if (col > wave * 16 + lk * 4 + r) s4[n][r] = -1e30f;
      }
    }
    // ---- online softmax (row = 16 lanes with same lane>>4) ----
#pragma unroll
    for (int r = 0; r < 4; r++) {
      float mx = fmaxf(fmaxf(s4[0][r], s4[1][r]), fmaxf(s4[2][r], s4[3][r]));
#pragma unroll
      for (int off = 1; off <= 8; off <<= 1) mx = fmaxf(mx, __shfl_xor(mx, off));
      const float mnew = fmaxf(m[r], mx);
      const float alpha = expf(m[r] - mnew);
      float ps = 0.f;
#pragma unroll
      for (int n = 0; n < 4; n++) {
        const float p = expf(s4[n][r] - mnew);
        s4[n][r] = p; ps += p;
      }
#pragma unroll
      for (int off = 1; off <= 8; off <<= 1) ps += __shfl_xor(ps, off);
      l[r] = l[r] * alpha + ps;
      m[r] = mnew;
#pragma unroll
      for (int n = 0; n < 4; n++) acc[n][r] *= alpha;
    }
    // ---- P (hi/lo) -> LDS, then barrier (cross-lane relayout) ----
#pragma unroll
    for (int n = 0; n < 4; n++)
#pragma unroll
      for (int r = 0; r < 4; r++) {
        const float p = s4[n][r];
        const bf16_t hi = (bf16_t)p;
        Ph[wave * 16 + lk * 4 + r][n * 16 + lcol] = hi;
        Po[wave * 16 + lk * 4 + r][n * 16 + lcol] = (bf16_t)(p - (float)hi);
      }
    __syncthreads();
    // ---- O += (Ph + Po) (Vh + Vl)  [3-term]  (A = P rows, B = V rows(d)) ----
#pragma unroll
    for (int ks = 0; ks < 2; ks++) {
      const bf16x8 pah = *(const bf16x8*)&Ph[wave * 16 + lcol][ks * 32 + lk * 8];
      const bf16x8 pao = *(const bf16x8*)&Po[wave * 16 + lcol][ks * 32 + lk * 8];
#pragma unroll
      for (int n = 0; n < 4; n++) {
        const int d = n * 16 + lcol;
        const int c0 = (ks * 32 + lk * 8 + (d & 56)) & 63;
        const bf16x8 bvh = *(const bf16x8*)&Vh[d][c0];
        const bf16x8 bvl = *(const bf16x8*)&Vl[d][c0];
        acc[n] = MFMA_BF16(pah, bvh, acc[n], 0, 0, 0);
        acc[n] = MFMA_BF16(pah, bvl, acc[n], 0, 0, 0);
        acc[n] = MFMA_BF16(pao, bvh, acc[n], 0, 0, 0);
      }
    }
  }
  // ---- epilogue: normalize, store bf16 ----
#pragma unroll
  for (int r = 0; r < 4; r++) {
    const int trow = qt * 64 + wave * 16 + lk * 4 + r;
    const float invl = 1.f / l[r];
#pragma unroll
    for (int n = 0; n < 4; n++)
      attnb[(size_t)trow * (NHH * HD) + h * HD + n * 16 + lcol] =
          (bf16_t)(acc[n][r] * invl);
  }
}

// ---------------- router logits (f32 h2) ----------------
__global__ void gate_logits_k(const float* __restrict__ h2, const float* __restrict__ gw,
                              float* __restrict__ logits) {
  const int t = blockIdx.x;
  const int e = threadIdx.x;  // 64
  const float* hp = h2 + (size_t)t * H_DIM;
  const float* gp = gw + (size_t)e * H_DIM;
  float s = 0.f;
  for (int i = 0; i < H_DIM; i += 4) {
    const float4 h4 = *(const float4*)(hp + i);
    const float4 g4 = *(const float4*)(gp + i);
    s += h4.x * g4.x + h4.y * g4.y + h4.z * g4.z + h4.w * g4.w;
  }
  logits[t * NE + e] = s;
}

// ---------------- routing: one thread per token ----------------
__global__ void route_k(const float* __restrict__ logits, const float* __restrict__ ebias,
                        int* __restrict__ topk_ids, float* __restrict__ topk_w) {
  const int t = blockIdx.x * 64 + threadIdx.x;
  if (t >= T_TOK) return;
  float s[NE], sc[NE];
  const float* lp = logits + t * NE;
#pragma unroll
  for (int e = 0; e < NE; e++) {
    const float v = 1.f / (1.f + expf(-lp[e]));
    s[e] = v;
    sc[e] = v + ebias[e];
  }
  float gsc[NGRP];
#pragma unroll
  for (int gi = 0; gi < NGRP; gi++) {
    float m1 = -1e30f, m2 = -1e30f;
#pragma unroll
    for (int j = 0; j < 8; j++) {
      const float v = sc[gi * 8 + j];
      if (v > m1) { m2 = m1; m1 = v; } else if (v > m2) m2 = v;
    }
    gsc[gi] = m1 + m2;
  }
  unsigned gmask = 0;
  for (int k2 = 0; k2 < TKG; k2++) {
    int bi = 0; float b = -3.4e38f;
#pragma unroll
    for (int gi = 0; gi < NGRP; gi++)
      if (!((gmask >> gi) & 1u) && gsc[gi] > b) { b = gsc[gi]; bi = gi; }
    gmask |= 1u << bi;
  }
  unsigned long long esel = 0ull;
  float wsum = 0.f;
  int ids[TOPKK]; float wv[TOPKK];
  for (int k2 = 0; k2 < TOPKK; k2++) {
    int bi = 0; float b = -3.4e38f;
    for (int e = 0; e < NE; e++) {
      if (((gmask >> (e >> 3)) & 1u) && !((esel >> e) & 1ull) && sc[e] > b) { b = sc[e]; bi = e; }
    }
    esel |= 1ull << bi;
    ids[k2] = bi;
    wv[k2] = s[bi];
    wsum += wv[k2];
  }
  const float norm = 2.5f / (wsum + 1e-20f);
#pragma unroll
  for (int k2 = 0; k2 < TOPKK; k2++) {
    topk_ids[t * TOPKK + k2] = ids[k2];
    topk_w[t * TOPKK + k2] = wv[k2] * norm;
  }
}

// ---------------- expert-token list construction ----------------
__global__ void count_k(const int* __restrict__ ids, int* __restrict__ counts) {
  const int idx = blockIdx.x * 256 + threadIdx.x;
  if (idx < NPOS) atomicAdd(&counts[ids[idx]], 1);
}

__global__ void offsets_k(const int* __restrict__ counts, int* __restrict__ offsets,
                          int* __restrict__ cursor) {
  if (threadIdx.x == 0 && blockIdx.x == 0) {
    int acc = 0;
    for (int e = 0; e < NE; e++) { offsets[e] = acc; cursor[e] = acc; acc += counts[e]; }
    offsets[NE] = acc;
  }
}

__global__ void scatter_k(const int* __restrict__ ids, const float* __restrict__ wts,
                          int* __restrict__ cursor, int* __restrict__ perm_tok,
                          float* __restrict__ perm_w) {
  const int idx = blockIdx.x * 256 + threadIdx.x;
  if (idx >= NPOS) return;
  const int e = ids[idx];
  const int pos = atomicAdd(&cursor[e], 1);
  perm_tok[pos] = idx >> 3;
  perm_w[pos] = wts[idx];
}

// ---------------- silu(g)*u from gu_e bf16 -> act bf16 ----------------
__global__ void act2_k(const bf16_t* __restrict__ gu_e, bf16_t* __restrict__ actb) {
  const int row = blockIdx.x;
  const int c = threadIdx.x;   // 0..255
  const float g = (float)gu_e[(size_t)row * 512 + c];
  const float u = (float)gu_e[(size_t)row * 512 + 256 + c];
  actb[(size_t)row * 256 + c] = (bf16_t)(g / (1.f + expf(-g)) * u);
}

// ---------------- shared expert activation: gu f32 -> sa bf16 ----------------
__global__ void sact_k(const float* __restrict__ gu, bf16_t* __restrict__ sa) {
  const int idx = blockIdx.x * 256 + threadIdx.x;   // < T*512
  const int t = idx >> 9, i = idx & 511;
  const float g = gu[(size_t)t * 1024 + i];
  const float u = gu[(size_t)t * 1024 + 512 + i];
  sa[idx] = (bf16_t)(g / (1.f + expf(-g)) * u);
}

// ---------------- launch ----------------
extern "C" void kernel_launch(void* const* d_in, const int* in_sizes, int n_in,
                              void* d_out, int out_size, void* d_ws, size_t ws_size,
                              hipStream_t stream) {
  const float* x         = (const float*)d_in[0];
  const int*   positions = (const int*)d_in[1];
  const float* ln1_w     = (const float*)d_in[2];
  const float* w_qkv     = (const float*)d_in[3];
  const float* w_o       = (const float*)d_in[4];
  const float* ln2_w     = (const float*)d_in[5];
  const float* gate_w    = (const float*)d_in[6];
  const float* ebias     = (const float*)d_in[7];
  const float* we_gate   = (const float*)d_in[8];
  const float* we_up     = (const float*)d_in[9];
  const float* we_down   = (const float*)d_in[10];
  const float* ws_gateup = (const float*)d_in[11];
  const float* ws_down   = (const float*)d_in[12];
  float* out = (float*)d_out;

  char* wsp = (char*)d_ws;
  size_t off = 0;
  auto alloc = [&](size_t bytes) {
    void* p = wsp + off;
    off += (bytes + 255) & ~(size_t)255;
    return p;
  };
  // qkv (12 MiB) + attnb (4 MiB) are contiguous; gu_e (16 MiB bf16) aliases both.
  float*  qkv    = (float*)alloc((size_t)T_TOK * QKV_N * 4);
  bf16_t* attnb  = (bf16_t*)alloc((size_t)T_TOK * H_DIM * 2);
  bf16_t* gu_e   = (bf16_t*)qkv;                       // [NPOS][512] bf16, used after attnb dead
  bf16_t* h1b    = (bf16_t*)alloc((size_t)T_TOK * H_DIM * 2);
  bf16_t* sa     = h1b;                                // [T][512] bf16, used after h1b dead
  float*  resid1 = (float*)alloc((size_t)T_TOK * H_DIM * 4);
  float*  h2f    = (float*)alloc((size_t)T_TOK * H_DIM * 4);
  bf16_t* h2b    = (bf16_t*)alloc((size_t)T_TOK * H_DIM * 2);
  float*  logits = (float*)alloc((size_t)T_TOK * NE * 4);
  int*    tids   = (int*)alloc((size_t)NPOS * 4);
  float*  tw     = (float*)alloc((size_t)NPOS * 4);
  int*    counts = (int*)alloc(NE * 4);
  int*    offs   = (int*)alloc((NE + 1) * 4);
  int*    cursor = (int*)alloc(NE * 4);
  int*    ptok   = (int*)alloc((size_t)NPOS * 4);
  float*  pw     = (float*)alloc((size_t)NPOS * 4);
  bf16_t* actb   = (bf16_t*)alloc((size_t)NPOS * EI * 2);
  float*  y      = (float*)alloc((size_t)T_TOK * H_DIM * 4);
  float*  gu     = (float*)alloc((size_t)T_TOK * 1024 * 4);
  // bf16 transposed weights
  bf16_t* wqkvT  = (bf16_t*)alloc((size_t)QKV_N * H_DIM * 2);
  bf16_t* woT    = (bf16_t*)alloc((size_t)H_DIM * H_DIM * 2);
  bf16_t* wsguT  = (bf16_t*)alloc((size_t)1024 * H_DIM * 2);
  bf16_t* wsdT   = (bf16_t*)alloc((size_t)H_DIM * ISH * 2);
  bf16_t* weT    = (bf16_t*)alloc((size_t)NE * 512 * H_DIM * 2);
  bf16_t* wdT    = (bf16_t*)alloc((size_t)NE * H_DIM * EI * 2);
  (void)ws_size; (void)in_sizes; (void)n_in; (void)out_size;

  // weight casts (transpose to [N][K] bf16)
  castT_k<<<dim3(QKV_N / 32, H_DIM / 32, 1), 256, 0, stream>>>(
      w_qkv, wqkvT, H_DIM, QKV_N, 0, 0, H_DIM, 0);
  castT_k<<<dim3(H_DIM / 32, H_DIM / 32, 1), 256, 0, stream>>>(
      w_o, woT, H_DIM, H_DIM, 0, 0, H_DIM, 0);
  castT_k<<<dim3(1024 / 32, H_DIM / 32, 1), 256, 0, stream>>>(
      ws_gateup, wsguT, H_DIM, 1024, 0, 0, H_DIM, 0);
  castT_k<<<dim3(H_DIM / 32, ISH / 32, 1), 256, 0, stream>>>(
      ws_down, wsdT, ISH, H_DIM, 0, 0, ISH, 0);
  castT_k<<<dim3(EI / 32, H_DIM / 32, NE), 256, 0, stream>>>(
      we_gate, weT, H_DIM, EI, (size_t)H_DIM * EI, (size_t)512 * H_DIM, H_DIM, 0);
  castT_k<<<dim3(EI / 32, H_DIM / 32, NE), 256, 0, stream>>>(
      we_up, weT, H_DIM, EI, (size_t)H_DIM * EI, (size_t)512 * H_DIM, H_DIM, 256);
  castT_k<<<dim3(H_DIM / 32, EI / 32, NE), 256, 0, stream>>>(
      we_down, wdT, EI, H_DIM, (size_t)EI * H_DIM, (size_t)H_DIM * EI, EI, 0);

  hipMemsetAsync(counts, 0, NE * 4, stream);
  hipMemsetAsync(y, 0, (size_t)T_TOK * H_DIM * 4, stream);

  // attention block
  rmsnorm_k<<<T_TOK, 256, 0, stream>>>(x, ln1_w, nullptr, h1b);
  mfma_gemm_k<<<dim3(QKV_N / 128, T_TOK / 128), 256, 0, stream>>>(
      h1b, wqkvT, nullptr, nullptr, qkv, T_TOK, QKV_N, H_DIM);
  rope_k<<<dim3(T_TOK, NHH + NKVH), 32, 0, stream>>>(qkv, positions);
  attn_k<<<dim3(NHH, T_TOK / 64), 256, 0, stream>>>(qkv, attnb);
  mfma_gemm_k<<<dim3(H_DIM / 128, T_TOK / 128), 256, 0, stream>>>(
      attnb, woT, x, nullptr, resid1, T_TOK, H_DIM, H_DIM);

  // MoE routing
  rmsnorm_k<<<T_TOK, 256, 0, stream>>>(resid1, ln2_w, h2f, h2b);
  gate_logits_k<<<T_TOK, 64, 0, stream>>>(h2f, gate_w, logits);
  route_k<<<T_TOK / 64, 64, 0, stream>>>(logits, ebias, tids, tw);
  count_k<<<NPOS / 256, 256, 0, stream>>>(tids, counts);
  offsets_k<<<1, 1, 0, stream>>>(counts, offs, cursor);
  scatter_k<<<NPOS / 256, 256, 0, stream>>>(tids, tw, cursor, ptok, pw);

  // routed experts (gu_e aliases qkv+attnb — both dead by now)
  mfma_gateup_k<<<dim3(512 / 128, T_TOK / 128, NE), 256, 0, stream>>>(
      h2b, weT, ptok, offs, gu_e);
  act2_k<<<NPOS, 256, 0, stream>>>(gu_e, actb);
  mfma_down_k<<<dim3(H_DIM / 128, T_TOK / 128, NE), 256, 0, stream>>>(
      actb, wdT, ptok, pw, offs, y);

  // shared expert + final combine
  mfma_gemm_k<<<dim3(1024 / 128, T_TOK / 128), 256, 0, stream>>>(
      h2b, wsguT, nullptr, nullptr, gu, T_TOK, 1024, H_DIM);
  sact_k<<<(T_TOK * ISH) / 256, 256, 0, stream>>>(gu, sa);
  mfma_gemm_k<<<dim3(H_DIM / 128, T_TOK / 128), 256, 0, stream>>>(
      sa, wsdT, resid1, y, out, T_TOK, H_DIM, ISH);
}

// Round 4
// 816.178 us; speedup vs baseline: 1.2233x; 1.0139x over previous
//
#include <hip/hip_runtime.h>
#include <hip/hip_bf16.h>
#include <math.h>

#define T_TOK 2048
#define H_DIM 1024
#define NHH 16
#define NKVH 4
#define HD 64
#define QKV_N 1536   // (16 + 2*4) * 64
#define NE 64
#define NGRP 8
#define TKG 4
#define TOPKK 8
#define EI 256
#define ISH 512
#define NPOS (T_TOK * TOPKK)   // 16384 expert-token slots

typedef __bf16 bf16_t;
typedef bf16_t bf16x8 __attribute__((ext_vector_type(8)));
typedef bf16_t bf16x4v __attribute__((ext_vector_type(4)));
typedef float f32x4 __attribute__((ext_vector_type(4)));

#define MFMA_BF16 __builtin_amdgcn_mfma_f32_16x16x32_bf16

// async global->LDS, 16B per lane. dst must be wave-uniform base (HW adds lane*16).
#define GLOAD16(gsrc, ldst)                                            \
  __builtin_amdgcn_global_load_lds(                                    \
      (const __attribute__((address_space(1))) void*)(gsrc),           \
      (__attribute__((address_space(3))) void*)(ldst), 16, 0, 0)

// ---------------- RMSNorm -> optional f32 out + bf16 out ----------------
__global__ void rmsnorm_k(const float* __restrict__ x, const float* __restrict__ w,
                          float* __restrict__ outf, bf16_t* __restrict__ outb) {
  const int t = blockIdx.x;
  const int tid = threadIdx.x;
  const float* xp = x + (size_t)t * H_DIM;
  const float4 x4 = *(const float4*)(xp + tid * 4);
  float s = x4.x * x4.x + x4.y * x4.y + x4.z * x4.z + x4.w * x4.w;
#pragma unroll
  for (int off = 32; off >= 1; off >>= 1) s += __shfl_xor(s, off);
  __shared__ float red[4];
  if ((tid & 63) == 0) red[tid >> 6] = s;
  __syncthreads();
  const float tot = red[0] + red[1] + red[2] + red[3];
  const float r = rsqrtf(tot / (float)H_DIM + 1e-6f);
  const float4 w4 = *(const float4*)(w + tid * 4);
  float4 o;
  o.x = x4.x * r * w4.x; o.y = x4.y * r * w4.y;
  o.z = x4.z * r * w4.z; o.w = x4.w * r * w4.w;
  if (outf) *(float4*)(outf + (size_t)t * H_DIM + tid * 4) = o;
  bf16x4v ob;
  ob[0] = (bf16_t)o.x; ob[1] = (bf16_t)o.y; ob[2] = (bf16_t)o.z; ob[3] = (bf16_t)o.w;
  *(bf16x4v*)(outb + (size_t)t * H_DIM + tid * 4) = ob;
}

// ---------------- transpose-cast f32 [R][C] -> bf16 [C][R] (per-expert strides) ----
__global__ void castT_k(const float* __restrict__ src, bf16_t* __restrict__ dst,
                        int R, int C, size_t srcStride, size_t dstStride,
                        int dstLD, int rowOff) {
  const int e = blockIdx.z;
  const float* sp = src + (size_t)e * srcStride;
  bf16_t* dp = dst + (size_t)e * dstStride;
  const int r0 = blockIdx.y * 32, c0 = blockIdx.x * 32;
  const int tid = threadIdx.x;
  __shared__ float tl[32][33];
  {
    const int rr = tid >> 3, cc4 = (tid & 7) * 4;
    const float4 v = *(const float4*)(sp + (size_t)(r0 + rr) * C + c0 + cc4);
    tl[rr][cc4 + 0] = v.x; tl[rr][cc4 + 1] = v.y;
    tl[rr][cc4 + 2] = v.z; tl[rr][cc4 + 3] = v.w;
  }
  __syncthreads();
  {
    const int cc = tid >> 3, rr4 = (tid & 7) * 4;
    bf16x4v o;
#pragma unroll
    for (int i = 0; i < 4; i++) o[i] = (bf16_t)tl[rr4 + i][cc];
    *(bf16x4v*)(dp + (size_t)(rowOff + c0 + cc) * dstLD + r0 + rr4) = o;
  }
}

// ================= MFMA GEMM family: 128x128 tile, BK=64 =================
// LDS: row-major [row][64k] with XOR swizzle on the 16B k-chunk index:
//   chunk(row,q) = row*8 + (q ^ ((row>>1)&7)),  q = k/8.
// Staged via global_load_lds: wave call j covers rows j*8..j*8+7; lane l
// fetches (row = j*8 + (l>>3), q = (l&7) ^ sw(row)) -> 8 lanes cover a full
// 128B row (perfect coalescing); read-side applies the same XOR (2-way bank
// alias = free). Fragment semantics identical to the reg-staged version.

// ---------------- MFMA GEMM: C[M,N] f32 = A[M,K]bf16 @ Bt[N,K]bf16 (+add0)(+add1) ----
__global__ __launch_bounds__(256) void mfma_gemm_k(
    const bf16_t* __restrict__ A, const bf16_t* __restrict__ Bt,
    const float* __restrict__ add0, const float* __restrict__ add1,
    float* __restrict__ C, int M, int N, int K) {
  __shared__ bf16_t Al[128 * 64];
  __shared__ bf16_t Bl[128 * 64];
  const int tid = threadIdx.x;
  const int lane = tid & 63, wave = tid >> 6;
  const int wm = wave >> 1, wn = wave & 1;
  const int lrow = lane & 15, lq = lane >> 4;
  const int m0 = blockIdx.y * 128, n0 = blockIdx.x * 128;
  f32x4 acc[4][4];
#pragma unroll
  for (int i = 0; i < 4; i++)
#pragma unroll
    for (int j = 0; j < 4; j++) acc[i][j] = (f32x4){0.f, 0.f, 0.f, 0.f};
  for (int k0 = 0; k0 < K; k0 += 64) {
    __syncthreads();
#pragma unroll
    for (int i = 0; i < 4; i++) {
      const int j = wave * 4 + i;
      const int rowl = j * 8 + (lane >> 3);
      const int q = (lane & 7) ^ ((rowl >> 1) & 7);
      GLOAD16(A + (size_t)(m0 + rowl) * K + k0 + q * 8, &Al[j * 512]);
      GLOAD16(Bt + (size_t)(n0 + rowl) * K + k0 + q * 8, &Bl[j * 512]);
    }
    __syncthreads();
#pragma unroll
    for (int kb = 0; kb < 2; kb++) {
      const int qq = kb * 4 + lq;
      bf16x8 af[4], bfr[4];
#pragma unroll
      for (int i = 0; i < 4; i++) {
        const int ra = wm * 64 + i * 16 + lrow;
        const int rb = wn * 64 + i * 16 + lrow;
        af[i]  = *(const bf16x8*)&Al[(ra * 8 + (qq ^ ((ra >> 1) & 7))) * 8];
        bfr[i] = *(const bf16x8*)&Bl[(rb * 8 + (qq ^ ((rb >> 1) & 7))) * 8];
      }
#pragma unroll
      for (int i = 0; i < 4; i++)
#pragma unroll
        for (int j = 0; j < 4; j++)
          acc[i][j] = MFMA_BF16(af[i], bfr[j], acc[i][j], 0, 0, 0);
    }
  }
#pragma unroll
  for (int i = 0; i < 4; i++)
#pragma unroll
    for (int r = 0; r < 4; r++) {
      const int m = m0 + wm * 64 + i * 16 + lq * 4 + r;
#pragma unroll
      for (int j = 0; j < 4; j++) {
        const int n = n0 + wn * 64 + j * 16 + lrow;
        float v = acc[i][j][r];
        if (add0) v += add0[(size_t)m * N + n];
        if (add1) v += add1[(size_t)m * N + n];
        C[(size_t)m * N + n] = v;
      }
    }
}

// ---------------- MoE gate+up grouped MFMA GEMM: rows gathered via ptok ----------
__global__ __launch_bounds__(256) void mfma_gateup_k(
    const bf16_t* __restrict__ h2b, const bf16_t* __restrict__ weT,
    const int* __restrict__ ptok, const int* __restrict__ offs,
    bf16_t* __restrict__ gu_e) {
  const int e = blockIdx.z;
  const int base = offs[e];
  const int cnt = offs[e + 1] - base;
  const int m0 = blockIdx.y * 128;
  if (m0 >= cnt) return;
  const int n0 = blockIdx.x * 128;
  __shared__ bf16_t Al[128 * 64];
  __shared__ bf16_t Bl[128 * 64];
  __shared__ int toks[128];
  const int tid = threadIdx.x;
  if (tid < 128) toks[tid] = ptok[base + min(m0 + tid, cnt - 1)];
  const int lane = tid & 63, wave = tid >> 6;
  const int wm = wave >> 1, wn = wave & 1;
  const int lrow = lane & 15, lq = lane >> 4;
  const bf16_t* Bt = weT + (size_t)e * 512 * 1024 + (size_t)n0 * 1024;
  f32x4 acc[4][4];
#pragma unroll
  for (int i = 0; i < 4; i++)
#pragma unroll
    for (int j = 0; j < 4; j++) acc[i][j] = (f32x4){0.f, 0.f, 0.f, 0.f};
  for (int k0 = 0; k0 < 1024; k0 += 64) {
    __syncthreads();   // first iteration also covers the toks[] fill
#pragma unroll
    for (int i = 0; i < 4; i++) {
      const int j = wave * 4 + i;
      const int rowl = j * 8 + (lane >> 3);
      const int q = (lane & 7) ^ ((rowl >> 1) & 7);
      GLOAD16(h2b + (size_t)toks[rowl] * 1024 + k0 + q * 8, &Al[j * 512]);
      GLOAD16(Bt + (size_t)rowl * 1024 + k0 + q * 8, &Bl[j * 512]);
    }
    __syncthreads();
#pragma unroll
    for (int kb = 0; kb < 2; kb++) {
      const int qq = kb * 4 + lq;
      bf16x8 af[4], bfr[4];
#pragma unroll
      for (int i = 0; i < 4; i++) {
        const int ra = wm * 64 + i * 16 + lrow;
        const int rb = wn * 64 + i * 16 + lrow;
        af[i]  = *(const bf16x8*)&Al[(ra * 8 + (qq ^ ((ra >> 1) & 7))) * 8];
        bfr[i] = *(const bf16x8*)&Bl[(rb * 8 + (qq ^ ((rb >> 1) & 7))) * 8];
      }
#pragma unroll
      for (int i = 0; i < 4; i++)
#pragma unroll
        for (int j = 0; j < 4; j++)
          acc[i][j] = MFMA_BF16(af[i], bfr[j], acc[i][j], 0, 0, 0);
    }
  }
#pragma unroll
  for (int i = 0; i < 4; i++)
#pragma unroll
    for (int r = 0; r < 4; r++) {
      const int mloc = m0 + wm * 64 + i * 16 + lq * 4 + r;
      if (mloc < cnt) {
#pragma unroll
        for (int j = 0; j < 4; j++) {
          const int n = n0 + wn * 64 + j * 16 + lrow;
          gu_e[(size_t)(base + mloc) * 512 + n] = (bf16_t)acc[i][j][r];
        }
      }
    }
}

// ---------------- MoE down grouped MFMA GEMM: weighted atomicAdd into y ----------
__global__ __launch_bounds__(256) void mfma_down_k(
    const bf16_t* __restrict__ actb, const bf16_t* __restrict__ wdT,
    const int* __restrict__ ptok, const float* __restrict__ pw,
    const int* __restrict__ offs, float* __restrict__ y) {
  const int e = blockIdx.z;
  const int base = offs[e];
  const int cnt = offs[e + 1] - base;
  const int m0 = blockIdx.y * 128;
  if (m0 >= cnt) return;
  const int n0 = blockIdx.x * 128;
  __shared__ bf16_t Al[128 * 64];
  __shared__ bf16_t Bl[128 * 64];
  const int tid = threadIdx.x;
  const int lane = tid & 63, wave = tid >> 6;
  const int wm = wave >> 1, wn = wave & 1;
  const int lrow = lane & 15, lq = lane >> 4;
  const bf16_t* Bt = wdT + (size_t)e * 1024 * 256 + (size_t)n0 * 256;
  f32x4 acc[4][4];
#pragma unroll
  for (int i = 0; i < 4; i++)
#pragma unroll
    for (int j = 0; j < 4; j++) acc[i][j] = (f32x4){0.f, 0.f, 0.f, 0.f};
  for (int k0 = 0; k0 < 256; k0 += 64) {
    __syncthreads();
#pragma unroll
    for (int i = 0; i < 4; i++) {
      const int j = wave * 4 + i;
      const int rowl = j * 8 + (lane >> 3);
      const int q = (lane & 7) ^ ((rowl >> 1) & 7);
      const int aRow = base + min(m0 + rowl, cnt - 1);
      GLOAD16(actb + (size_t)aRow * 256 + k0 + q * 8, &Al[j * 512]);
      GLOAD16(Bt + (size_t)rowl * 256 + k0 + q * 8, &Bl[j * 512]);
    }
    __syncthreads();
#pragma unroll
    for (int kb = 0; kb < 2; kb++) {
      const int qq = kb * 4 + lq;
      bf16x8 af[4], bfr[4];
#pragma unroll
      for (int i = 0; i < 4; i++) {
        const int ra = wm * 64 + i * 16 + lrow;
        const int rb = wn * 64 + i * 16 + lrow;
        af[i]  = *(const bf16x8*)&Al[(ra * 8 + (qq ^ ((ra >> 1) & 7))) * 8];
        bfr[i] = *(const bf16x8*)&Bl[(rb * 8 + (qq ^ ((rb >> 1) & 7))) * 8];
      }
#pragma unroll
      for (int i = 0; i < 4; i++)
#pragma unroll
        for (int j = 0; j < 4; j++)
          acc[i][j] = MFMA_BF16(af[i], bfr[j], acc[i][j], 0, 0, 0);
    }
  }
#pragma unroll
  for (int i = 0; i < 4; i++)
#pragma unroll
    for (int r = 0; r < 4; r++) {
      const int mloc = m0 + wm * 64 + i * 16 + lq * 4 + r;
      if (mloc < cnt) {
        const float wv = pw[base + mloc];
        const int tok = ptok[base + mloc];
#pragma unroll
        for (int j = 0; j < 4; j++) {
          const int n = n0 + wn * 64 + j * 16 + lrow;
          atomicAdd(&y[(size_t)tok * H_DIM + n], wv * acc[i][j][r]);
        }
      }
    }
}

// ---------------- RoPE (neox, in-place on q and k regions of qkv), f32 ----------------
__global__ void rope_k(float* __restrict__ qkv, const int* __restrict__ positions) {
  const int t = blockIdx.x, h = blockIdx.y;
  const int i = threadIdx.x;                  // 0..31
  const float inv = exp2f((float)i * (-13.287712379549449f / 32.0f));
  const float f = (float)positions[t] * inv;
  float sn, c;
  sincosf(f, &sn, &c);
  float* p = qkv + (size_t)t * QKV_N + h * HD;
  const float x1 = p[i], x2 = p[i + 32];
  p[i] = x1 * c - x2 * sn;
  p[i + 32] = x2 * c + x1 * sn;
}

// ---------------- KV pre-convert: roped K/V f32 -> hi/lo bf16, once ----------------
// K: row-major [g][t][64] (hi, lo). V: per 64-token tile, transposed+rotated
// [g][tile][d][col] with col = (srow + (d&56)) & 63 — exactly the layout attn's
// PV step reads, so attn staging becomes pure 16B copies.
__global__ __launch_bounds__(256) void kvprep_k(
    const float* __restrict__ qkv, bf16_t* __restrict__ kh, bf16_t* __restrict__ kl,
    bf16_t* __restrict__ vh, bf16_t* __restrict__ vl) {
  const int tile = blockIdx.x, g = blockIdx.y;
  const int tid = threadIdx.x;
  const int srow = tid >> 2, scb = tid & 3;
  const int t = tile * 64 + srow;
  const float* kp = qkv + (size_t)t * QKV_N + NHH * HD + g * HD + scb * 16;
  const float* vp = kp + NKVH * HD;
  __shared__ bf16_t Vsh[64][72];
  __shared__ bf16_t Vsl[64][72];
  // K hi/lo straight copy-out
  {
    const float4 k0 = *(const float4*)(kp + 0);
    const float4 k1 = *(const float4*)(kp + 4);
    const float4 k2 = *(const float4*)(kp + 8);
    const float4 k3 = *(const float4*)(kp + 12);
    const float kv[16] = {k0.x, k0.y, k0.z, k0.w, k1.x, k1.y, k1.z, k1.w,
                          k2.x, k2.y, k2.z, k2.w, k3.x, k3.y, k3.z, k3.w};
    bf16x8 h0, h1, o0, o1;
#pragma unroll
    for (int j = 0; j < 8; j++) {
      const bf16_t hi = (bf16_t)kv[j];
      h0[j] = hi; o0[j] = (bf16_t)(kv[j] - (float)hi);
      const bf16_t hi2 = (bf16_t)kv[j + 8];
      h1[j] = hi2; o1[j] = (bf16_t)(kv[j + 8] - (float)hi2);
    }
    bf16_t* khp = kh + ((size_t)g * T_TOK + t) * 64 + scb * 16;
    bf16_t* klp = kl + ((size_t)g * T_TOK + t) * 64 + scb * 16;
    *(bf16x8*)(khp) = h0; *(bf16x8*)(khp + 8) = h1;
    *(bf16x8*)(klp) = o0; *(bf16x8*)(klp + 8) = o1;
  }
  // V: rotated transpose into LDS (scalar scatter), then coalesced write-out
  {
    const float4 v0 = *(const float4*)(vp + 0);
    const float4 v1 = *(const float4*)(vp + 4);
    const float4 v2 = *(const float4*)(vp + 8);
    const float4 v3 = *(const float4*)(vp + 12);
    const float vv[16] = {v0.x, v0.y, v0.z, v0.w, v1.x, v1.y, v1.z, v1.w,
                          v2.x, v2.y, v2.z, v2.w, v3.x, v3.y, v3.z, v3.w};
#pragma unroll
    for (int r2 = 0; r2 < 16; r2++) {
      const int d = scb * 16 + r2;
      const int col = (srow + (d & 56)) & 63;
      const bf16_t hi = (bf16_t)vv[r2];
      Vsh[d][col] = hi;
      Vsl[d][col] = (bf16_t)(vv[r2] - (float)hi);
    }
  }
  __syncthreads();
  {
    const size_t ob = (((size_t)g * (T_TOK / 64) + tile) * 64 + srow) * 64 + scb * 16;
    *(bf16x8*)(vh + ob)     = *(const bf16x8*)&Vsh[srow][scb * 16];
    *(bf16x8*)(vh + ob + 8) = *(const bf16x8*)&Vsh[srow][scb * 16 + 8];
    *(bf16x8*)(vl + ob)     = *(const bf16x8*)&Vsl[srow][scb * 16];
    *(bf16x8*)(vl + ob + 8) = *(const bf16x8*)&Vsl[srow][scb * 16 + 8];
  }
}

// ---------------- MFMA flash attention, full hi/lo split (f32-equivalent) ------
// Identical math to round 3 (passing, absmax == f32 baseline). Staging now reads
// pre-converted bf16 hi/lo K/V — pure vector copies, no per-tile conversions.
__global__ __launch_bounds__(256) void attn_k(
    const float* __restrict__ qkv, const bf16_t* __restrict__ kh_g,
    const bf16_t* __restrict__ kl_g, const bf16_t* __restrict__ vh_g,
    const bf16_t* __restrict__ vl_g, bf16_t* __restrict__ attnb) {
  const int h = blockIdx.x;
  const int qt = (T_TOK / 64 - 1) - blockIdx.y;   // heavy tiles first
  const int g = h >> 2;
  const int tid = threadIdx.x;
  const int lane = tid & 63, wave = tid >> 6;
  const int lcol = lane & 15, lk = lane >> 4;

  __shared__ bf16_t Kh[64][72];
  __shared__ bf16_t Ko[64][72];
  __shared__ bf16_t Vh[64][72];
  __shared__ bf16_t Vl[64][72];
  __shared__ bf16_t Ph[64][72];
  __shared__ bf16_t Po[64][72];

  // --- Q fragments (hi/lo) in registers, pre-scaled by D^-1/2 ---
  bf16x8 aqh[2], aql[2];
  {
    const int qrow = qt * 64 + wave * 16 + lcol;
    const float* qp = qkv + (size_t)qrow * QKV_N + h * HD + lk * 8;
#pragma unroll
    for (int ks = 0; ks < 2; ks++) {
      const float4 a = *(const float4*)(qp + ks * 32);
      const float4 b = *(const float4*)(qp + ks * 32 + 4);
      const float qv[8] = {a.x, a.y, a.z, a.w, b.x, b.y, b.z, b.w};
#pragma unroll
      for (int j = 0; j < 8; j++) {
        const float v = qv[j] * 0.125f;
        const bf16_t hi = (bf16_t)v;
        aqh[ks][j] = hi;
        aql[ks][j] = (bf16_t)(v - (float)hi);
      }
    }
  }

  float m[4], l[4];
  f32x4 acc[4];
#pragma unroll
  for (int r = 0; r < 4; r++) { m[r] = -1e30f; l[r] = 0.f; }
#pragma unroll
  for (int n = 0; n < 4; n++) acc[n] = (f32x4){0.f, 0.f, 0.f, 0.f};

  const bf16_t* khB = kh_g + (size_t)g * T_TOK * 64;
  const bf16_t* klB = kl_g + (size_t)g * T_TOK * 64;
  const bf16_t* vhB = vh_g + (size_t)g * (T_TOK / 64) * 64 * 64;
  const bf16_t* vlB = vl_g + (size_t)g * (T_TOK / 64) * 64 * 64;
  const int srow = tid >> 2;      // staging: row (K: token, V: d) 0..63
  const int scb = tid & 3;        // staging: 16-elem col block

  for (int s0 = 0; s0 <= qt * 64; s0 += 64) {
    __syncthreads();
    // ---- stage K (row-major) and V (pre-rotated transpose): pure copies ----
    {
      const size_t kb0 = (size_t)(s0 + srow) * 64 + scb * 16;
      *(bf16x8*)&Kh[srow][scb * 16]     = *(const bf16x8*)(khB + kb0);
      *(bf16x8*)&Kh[srow][scb * 16 + 8] = *(const bf16x8*)(khB + kb0 + 8);
      *(bf16x8*)&Ko[srow][scb * 16]     = *(const bf16x8*)(klB + kb0);
      *(bf16x8*)&Ko[srow][scb * 16 + 8] = *(const bf16x8*)(klB + kb0 + 8);
      const size_t vb0 = ((size_t)(s0 >> 6) * 64 + srow) * 64 + scb * 16;
      *(bf16x8*)&Vh[srow][scb * 16]     = *(const bf16x8*)(vhB + vb0);
      *(bf16x8*)&Vh[srow][scb * 16 + 8] = *(const bf16x8*)(vhB + vb0 + 8);
      *(bf16x8*)&Vl[srow][scb * 16]     = *(const bf16x8*)(vlB + vb0);
      *(bf16x8*)&Vl[srow][scb * 16 + 8] = *(const bf16x8*)(vlB + vb0 + 8);
    }
    __syncthreads();
    // ---- S = Q K^T  (per wave: 16 rows x 64 cols), 3-term hi/lo ----
    f32x4 s4[4];
#pragma unroll
    for (int n = 0; n < 4; n++) s4[n] = (f32x4){0.f, 0.f, 0.f, 0.f};
#pragma unroll
    for (int ks = 0; ks < 2; ks++) {
#pragma unroll
      for (int n = 0; n < 4; n++) {
        const bf16x8 bh = *(const bf16x8*)&Kh[n * 16 + lcol][ks * 32 + lk * 8];
        const bf16x8 bo = *(const bf16x8*)&Ko[n * 16 + lcol][ks * 32 + lk * 8];
        s4[n] = MFMA_BF16(aqh[ks], bh, s4[n], 0, 0, 0);
        s4[n] = MFMA_BF16(aqh[ks], bo, s4[n], 0, 0, 0);
        s4[n] = MFMA_BF16(aql[ks], bh, s4[n], 0, 0, 0);
      }
    }
    // ---- causal mask on diagonal tile ----
    if (s0 == qt * 64) {
#pragma unroll
      for (int n = 0; n < 4; n++) {
        const int col = n * 16 + lcol;
#pragma unroll
        for (int r = 0; r < 4; r++)
          if (col > wave * 16 + lk * 4 + r) s4[n][r] = -1e30f;
      }
    }
    // ---- online softmax (row = 16 lanes with same lane>>4) ----
#pragma unroll
    for (int r = 0; r < 4; r++) {
      float mx = fmaxf(fmaxf(s4[0][r], s4[1][r]), fmaxf(s4[2][r], s4[3][r]));
#pragma unroll
      for (int off = 1; off <= 8; off <<= 1) mx = fmaxf(mx, __shfl_xor(mx, off));
      const float mnew = fmaxf(m[r], mx);
      const float alpha = expf(m[r] - mnew);
      float ps = 0.f;
#pragma unroll
      for (int n = 0; n < 4; n++) {
        const float p = expf(s4[n][r] - mnew);
        s4[n][r] = p; ps += p;
      }
#pragma unroll
      for (int off = 1; off <= 8; off <<= 1) ps += __shfl_xor(ps, off);
      l[r] = l[r] * alpha + ps;
      m[r] = mnew;
#pragma unroll
      for (int n = 0; n < 4; n++) acc[n][r] *= alpha;
    }
    // ---- P (hi/lo) -> LDS, then barrier (cross-lane relayout) ----
#pragma unroll
    for (int n = 0; n < 4; n++)
#pragma unroll
      for (int r = 0; r < 4; r++) {
        const float p = s4[n][r];
        const bf16_t hi = (bf16_t)p;
        Ph[wave * 16 + lk * 4 + r][n * 16 + lcol] = hi;
        Po[wave * 16 + lk * 4 + r][n * 16 + lcol] = (bf16_t)(p - (float)hi);
      }
    __syncthreads();
    // ---- O += (Ph + Po) (Vh + Vl)  [3-term] ----
#pragma unroll
    for (int ks = 0; ks < 2; ks++) {
      const bf16x8 pah = *(const bf16x8*)&Ph[wave * 16 + lcol][ks * 32 + lk * 8];
      const bf16x8 pao = *(const bf16x8*)&Po[wave * 16 + lcol][ks * 32 + lk * 8];
#pragma unroll
      for (int n = 0; n < 4; n++) {
        const int d = n * 16 + lcol;
        const int c0 = (ks * 32 + lk * 8 + (d & 56)) & 63;
        const bf16x8 bvh = *(const bf16x8*)&Vh[d][c0];
        const bf16x8 bvl = *(const bf16x8*)&Vl[d][c0];
        acc[n] = MFMA_BF16(pah, bvh, acc[n], 0, 0, 0);
        acc[n] = MFMA_BF16(pah, bvl, acc[n], 0, 0, 0);
        acc[n] = MFMA_BF16(pao, bvh, acc[n], 0, 0, 0);
      }
    }
  }
  // ---- epilogue: normalize, store bf16 ----
#pragma unroll
  for (int r = 0; r < 4; r++) {
    const int trow = qt * 64 + wave * 16 + lk * 4 + r;
    const float invl = 1.f / l[r];
#pragma unroll
    for (int n = 0; n < 4; n++)
      attnb[(size_t)trow * (NHH * HD) + h * HD + n * 16 + lcol] =
          (bf16_t)(acc[n][r] * invl);
  }
}

// ---------------- router logits (f32 h2) ----------------
__global__ void gate_logits_k(const float* __restrict__ h2, const float* __restrict__ gw,
                              float* __restrict__ logits) {
  const int t = blockIdx.x;
  const int e = threadIdx.x;  // 64
  const float* hp = h2 + (size_t)t * H_DIM;
  const float* gp = gw + (size_t)e * H_DIM;
  float s = 0.f;
  for (int i = 0; i < H_DIM; i += 4) {
    const float4 h4 = *(const float4*)(hp + i);
    const float4 g4 = *(const float4*)(gp + i);
    s += h4.x * g4.x + h4.y * g4.y + h4.z * g4.z + h4.w * g4.w;
  }
  logits[t * NE + e] = s;
}

// ---------------- routing: one thread per token ----------------
__global__ void route_k(const float* __restrict__ logits, const float* __restrict__ ebias,
                        int* __restrict__ topk_ids, float* __restrict__ topk_w) {
  const int t = blockIdx.x * 64 + threadIdx.x;
  if (t >= T_TOK) return;
  float s[NE], sc[NE];
  const float* lp = logits + t * NE;
#pragma unroll
  for (int e = 0; e < NE; e++) {
    const float v = 1.f / (1.f + expf(-lp[e]));
    s[e] = v;
    sc[e] = v + ebias[e];
  }
  float gsc[NGRP];
#pragma unroll
  for (int gi = 0; gi < NGRP; gi++) {
    float m1 = -1e30f, m2 = -1e30f;
#pragma unroll
    for (int j = 0; j < 8; j++) {
      const float v = sc[gi * 8 + j];
      if (v > m1) { m2 = m1; m1 = v; } else if (v > m2) m2 = v;
    }
    gsc[gi] = m1 + m2;
  }
  unsigned gmask = 0;
  for (int k2 = 0; k2 < TKG; k2++) {
    int bi = 0; float b = -3.4e38f;
#pragma unroll
    for (int gi = 0; gi < NGRP; gi++)
      if (!((gmask >> gi) & 1u) && gsc[gi] > b) { b = gsc[gi]; bi = gi; }
    gmask |= 1u << bi;
  }
  unsigned long long esel = 0ull;
  float wsum = 0.f;
  int ids[TOPKK]; float wv[TOPKK];
  for (int k2 = 0; k2 < TOPKK; k2++) {
    int bi = 0; float b = -3.4e38f;
    for (int e = 0; e < NE; e++) {
      if (((gmask >> (e >> 3)) & 1u) && !((esel >> e) & 1ull) && sc[e] > b) { b = sc[e]; bi = e; }
    }
    esel |= 1ull << bi;
    ids[k2] = bi;
    wv[k2] = s[bi];
    wsum += wv[k2];
  }
  const float norm = 2.5f / (wsum + 1e-20f);
#pragma unroll
  for (int k2 = 0; k2 < TOPKK; k2++) {
    topk_ids[t * TOPKK + k2] = ids[k2];
    topk_w[t * TOPKK + k2] = wv[k2] * norm;
  }
}

// ---------------- expert-token list construction ----------------
__global__ void count_k(const int* __restrict__ ids, int* __restrict__ counts) {
  const int idx = blockIdx.x * 256 + threadIdx.x;
  if (idx < NPOS) atomicAdd(&counts[ids[idx]], 1);
}

__global__ void offsets_k(const int* __restrict__ counts, int* __restrict__ offsets,
                          int* __restrict__ cursor) {
  if (threadIdx.x == 0 && blockIdx.x == 0) {
    int acc = 0;
    for (int e = 0; e < NE; e++) { offsets[e] = acc; cursor[e] = acc; acc += counts[e]; }
    offsets[NE] = acc;
  }
}

__global__ void scatter_k(const int* __restrict__ ids, const float* __restrict__ wts,
                          int* __restrict__ cursor, int* __restrict__ perm_tok,
                          float* __restrict__ perm_w) {
  const int idx = blockIdx.x * 256 + threadIdx.x;
  if (idx >= NPOS) return;
  const int e = ids[idx];
  const int pos = atomicAdd(&cursor[e], 1);
  perm_tok[pos] = idx >> 3;
  perm_w[pos] = wts[idx];
}

// ---------------- silu(g)*u from gu_e bf16 -> act bf16 ----------------
__global__ void act2_k(const bf16_t* __restrict__ gu_e, bf16_t* __restrict__ actb) {
  const int row = blockIdx.x;
  const int c = threadIdx.x;   // 0..255
  const float g = (float)gu_e[(size_t)row * 512 + c];
  const float u = (float)gu_e[(size_t)row * 512 + 256 + c];
  actb[(size_t)row * 256 + c] = (bf16_t)(g / (1.f + expf(-g)) * u);
}

// ---------------- shared expert activation: gu f32 -> sa bf16 ----------------
__global__ void sact_k(const float* __restrict__ gu, bf16_t* __restrict__ sa) {
  const int idx = blockIdx.x * 256 + threadIdx.x;   // < T*512
  const int t = idx >> 9, i = idx & 511;
  const float g = gu[(size_t)t * 1024 + i];
  const float u = gu[(size_t)t * 1024 + 512 + i];
  sa[idx] = (bf16_t)(g / (1.f + expf(-g)) * u);
}

// ---------------- launch ----------------
extern "C" void kernel_launch(void* const* d_in, const int* in_sizes, int n_in,
                              void* d_out, int out_size, void* d_ws, size_t ws_size,
                              hipStream_t stream) {
  const float* x         = (const float*)d_in[0];
  const int*   positions = (const int*)d_in[1];
  const float* ln1_w     = (const float*)d_in[2];
  const float* w_qkv     = (const float*)d_in[3];
  const float* w_o       = (const float*)d_in[4];
  const float* ln2_w     = (const float*)d_in[5];
  const float* gate_w    = (const float*)d_in[6];
  const float* ebias     = (const float*)d_in[7];
  const float* we_gate   = (const float*)d_in[8];
  const float* we_up     = (const float*)d_in[9];
  const float* we_down   = (const float*)d_in[10];
  const float* ws_gateup = (const float*)d_in[11];
  const float* ws_down   = (const float*)d_in[12];
  float* out = (float*)d_out;

  char* wsp = (char*)d_ws;
  size_t off = 0;
  auto alloc = [&](size_t bytes) {
    void* p = wsp + off;
    off += (bytes + 255) & ~(size_t)255;
    return p;
  };
  // qkv (12 MiB) + attnb (4 MiB) are contiguous; gu_e (16 MiB bf16) aliases both.
  float*  qkv    = (float*)alloc((size_t)T_TOK * QKV_N * 4);
  bf16_t* attnb  = (bf16_t*)alloc((size_t)T_TOK * H_DIM * 2);
  bf16_t* gu_e   = (bf16_t*)qkv;                       // [NPOS][512] bf16, used after attnb dead
  bf16_t* h1b    = (bf16_t*)alloc((size_t)T_TOK * H_DIM * 2);
  bf16_t* sa     = h1b;                                // [T][512] bf16, used after h1b dead
  float*  resid1 = (float*)alloc((size_t)T_TOK * H_DIM * 4);
  float*  h2f    = (float*)alloc((size_t)T_TOK * H_DIM * 4);
  bf16_t* h2b    = (bf16_t*)alloc((size_t)T_TOK * H_DIM * 2);
  float*  logits = (float*)alloc((size_t)T_TOK * NE * 4);
  int*    tids   = (int*)alloc((size_t)NPOS * 4);
  float*  tw     = (float*)alloc((size_t)NPOS * 4);
  int*    counts = (int*)alloc(NE * 4);
  int*    offs   = (int*)alloc((NE + 1) * 4);
  int*    cursor = (int*)alloc(NE * 4);
  int*    ptok   = (int*)alloc((size_t)NPOS * 4);
  float*  pw     = (float*)alloc((size_t)NPOS * 4);
  bf16_t* actb   = (bf16_t*)alloc((size_t)NPOS * EI * 2);
  float*  y      = (float*)alloc((size_t)T_TOK * H_DIM * 4);
  float*  gu     = (float*)alloc((size_t)T_TOK * 1024 * 4);
  // bf16 transposed weights
  bf16_t* wqkvT  = (bf16_t*)alloc((size_t)QKV_N * H_DIM * 2);
  bf16_t* woT    = (bf16_t*)alloc((size_t)H_DIM * H_DIM * 2);
  bf16_t* wsguT  = (bf16_t*)alloc((size_t)1024 * H_DIM * 2);
  bf16_t* wsdT   = (bf16_t*)alloc((size_t)H_DIM * ISH * 2);
  bf16_t* weT    = (bf16_t*)alloc((size_t)NE * 512 * H_DIM * 2);
  bf16_t* wdT    = (bf16_t*)alloc((size_t)NE * H_DIM * EI * 2);
  // pre-converted KV (hi/lo); V pre-transposed+rotated per 64-tile
  bf16_t* kvkh   = (bf16_t*)alloc((size_t)NKVH * T_TOK * 64 * 2);
  bf16_t* kvkl   = (bf16_t*)alloc((size_t)NKVH * T_TOK * 64 * 2);
  bf16_t* kvvh   = (bf16_t*)alloc((size_t)NKVH * T_TOK * 64 * 2);
  bf16_t* kvvl   = (bf16_t*)alloc((size_t)NKVH * T_TOK * 64 * 2);
  (void)ws_size; (void)in_sizes; (void)n_in; (void)out_size;

  // weight casts (transpose to [N][K] bf16)
  castT_k<<<dim3(QKV_N / 32, H_DIM / 32, 1), 256, 0, stream>>>(
      w_qkv, wqkvT, H_DIM, QKV_N, 0, 0, H_DIM, 0);
  castT_k<<<dim3(H_DIM / 32, H_DIM / 32, 1), 256, 0, stream>>>(
      w_o, woT, H_DIM, H_DIM, 0, 0, H_DIM, 0);
  castT_k<<<dim3(1024 / 32, H_DIM / 32, 1), 256, 0, stream>>>(
      ws_gateup, wsguT, H_DIM, 1024, 0, 0, H_DIM, 0);
  castT_k<<<dim3(H_DIM / 32, ISH / 32, 1), 256, 0, stream>>>(
      ws_down, wsdT, ISH, H_DIM, 0, 0, ISH, 0);
  castT_k<<<dim3(EI / 32, H_DIM / 32, NE), 256, 0, stream>>>(
      we_gate, weT, H_DIM, EI, (size_t)H_DIM * EI, (size_t)512 * H_DIM, H_DIM, 0);
  castT_k<<<dim3(EI / 32, H_DIM / 32, NE), 256, 0, stream>>>(
      we_up, weT, H_DIM, EI, (size_t)H_DIM * EI, (size_t)512 * H_DIM, H_DIM, 256);
  castT_k<<<dim3(H_DIM / 32, EI / 32, NE), 256, 0, stream>>>(
      we_down, wdT, EI, H_DIM, (size_t)EI * H_DIM, (size_t)H_DIM * EI, EI, 0);

  hipMemsetAsync(counts, 0, NE * 4, stream);
  hipMemsetAsync(y, 0, (size_t)T_TOK * H_DIM * 4, stream);

  // attention block
  rmsnorm_k<<<T_TOK, 256, 0, stream>>>(x, ln1_w, nullptr, h1b);
  mfma_gemm_k<<<dim3(QKV_N / 128, T_TOK / 128), 256, 0, stream>>>(
      h1b, wqkvT, nullptr, nullptr, qkv, T_TOK, QKV_N, H_DIM);
  rope_k<<<dim3(T_TOK, NHH + NKVH), 32, 0, stream>>>(qkv, positions);
  kvprep_k<<<dim3(T_TOK / 64, NKVH), 256, 0, stream>>>(qkv, kvkh, kvkl, kvvh, kvvl);
  attn_k<<<dim3(NHH, T_TOK / 64), 256, 0, stream>>>(qkv, kvkh, kvkl, kvvh, kvvl, attnb);
  mfma_gemm_k<<<dim3(H_DIM / 128, T_TOK / 128), 256, 0, stream>>>(
      attnb, woT, x, nullptr, resid1, T_TOK, H_DIM, H_DIM);

  // MoE routing
  rmsnorm_k<<<T_TOK, 256, 0, stream>>>(resid1, ln2_w, h2f, h2b);
  gate_logits_k<<<T_TOK, 64, 0, stream>>>(h2f, gate_w, logits);
  route_k<<<T_TOK / 64, 64, 0, stream>>>(logits, ebias, tids, tw);
  count_k<<<NPOS / 256, 256, 0, stream>>>(tids, counts);
  offsets_k<<<1, 1, 0, stream>>>(counts, offs, cursor);
  scatter_k<<<NPOS / 256, 256, 0, stream>>>(tids, tw, cursor, ptok, pw);

  // routed experts (gu_e aliases qkv+attnb — both dead by now)
  mfma_gateup_k<<<dim3(512 / 128, T_TOK / 128, NE), 256, 0, stream>>>(
      h2b, weT, ptok, offs, gu_e);
  act2_k<<<NPOS, 256, 0, stream>>>(gu_e, actb);
  mfma_down_k<<<dim3(H_DIM / 128, T_TOK / 128, NE), 256, 0, stream>>>(
      actb, wdT, ptok, pw, offs, y);

  // shared expert + final combine
  mfma_gemm_k<<<dim3(1024 / 128, T_TOK / 128), 256, 0, stream>>>(
      h2b, wsguT, nullptr, nullptr, gu, T_TOK, 1024, H_DIM);
  sact_k<<<(T_TOK * ISH) / 256, 256, 0, stream>>>(gu, sa);
  mfma_gemm_k<<<dim3(H_DIM / 128, T_TOK / 128), 256, 0, stream>>>(
      sa, wsdT, resid1, y, out, T_TOK, H_DIM, ISH);
}